// Round 4
// baseline (645.809 us; speedup 1.0000x reference)
//
#include <hip/hip_runtime.h>
#include <hip/hip_bf16.h>

#define N_ROWS 8192
#define BATCH 4096
#define DIM 256

#define MTILE 128       // rows per block (2 waves x 64 rows)
#define NCHUNK 16       // col chunks
#define CCHUNK 512      // cols per chunk
#define CT 16           // cols per LDS tile
#define LDSROW 528      // 512 data bytes + 16 pad
#define LDSBUF (CT * LDSROW)
#define NBLOCKS (64 * NCHUNK)
#define KEXP 2.8853900817779268f   // 2*log2(e): exp(2*dot) = exp2(dot*KEXP)

typedef __attribute__((ext_vector_type(8))) short bfrag8;
typedef __attribute__((ext_vector_type(4))) float facc4;

// ---------------- Kernel A: normalize + cast to bf16 -------------------
__global__ __launch_bounds__(256) void normalize_kernel(
    const float* __restrict__ zA, const float* __restrict__ zB,
    __hip_bfloat16* __restrict__ zn, unsigned* __restrict__ done) {
    int tid = threadIdx.x;
    int wave = tid >> 6, lane = tid & 63;
    int row = blockIdx.x * 4 + wave;
    if (blockIdx.x == 0 && tid == 0) *done = 0u;   // completion counter for main
    const float* src = (row < BATCH) ? (zA + (size_t)row * DIM)
                                     : (zB + (size_t)(row - BATCH) * DIM);
    float4 v = ((const float4*)src)[lane];
    float ss = v.x * v.x + v.y * v.y + v.z * v.z + v.w * v.w;
    #pragma unroll
    for (int m = 32; m; m >>= 1) ss += __shfl_xor(ss, m);
    float inv = 1.0f / fmaxf(sqrtf(ss), 1e-8f);
    union { ushort4 u; __hip_bfloat16 h[4]; } o;
    o.h[0] = __float2bfloat16(v.x * inv);
    o.h[1] = __float2bfloat16(v.y * inv);
    o.h[2] = __float2bfloat16(v.z * inv);
    o.h[3] = __float2bfloat16(v.w * inv);
    ((ushort4*)zn)[(size_t)row * (DIM / 4) + lane] = o.u;
}

// ---------------- Kernel B: streaming sim + exp-sum + fused finalize ----
// grid (64 row-blocks, 16 col chunks); block 128 = 2 waves x 64 rows.
__global__ __launch_bounds__(128, 4) void ntxent_main(
    const __hip_bfloat16* __restrict__ zn_,
    float* __restrict__ ep, float* __restrict__ pp,
    unsigned* __restrict__ done, float* __restrict__ out) {
    const char* zn = (const char*)zn_;
    __shared__ char lds[2 * LDSBUF] __attribute__((aligned(16)));
    int tid = threadIdx.x, lane = tid & 63, wave = tid >> 6;
    int quad = lane >> 4, l15 = lane & 15;
    int row0 = blockIdx.x * MTILE + wave * 64;   // 64-aligned
    int chunk = blockIdx.y;
    int cc = chunk * CCHUNK;

    // A fragments: 4 tiles of 16 rows. row = row0 + s*16 + l15, k = ks*32 + quad*8 + j
    bfrag8 a[4][8];
    #pragma unroll
    for (int s = 0; s < 4; s++) {
        const char* ap = zn + (size_t)(row0 + s * 16 + l15) * 512 + quad * 16;
        #pragma unroll
        for (int ks = 0; ks < 8; ks++)
            a[s][ks] = *(const bfrag8*)(ap + ks * 64);
    }

    float es[4][4], ps[4][4];
    #pragma unroll
    for (int s = 0; s < 4; s++)
        #pragma unroll
        for (int r = 0; r < 4; r++) { es[s][r] = 0.f; ps[s][r] = 0.f; }

    // staging: tile = 16 cols x 512 B = 512 x 16B; 128 threads x 4 chunks of 16B
    int col0 = tid >> 3, sub = tid & 7;          // col 0..15, 64B sub-run
    unsigned lofs = col0 * LDSROW + sub * 64;
    unsigned gofs = col0 * 512 + sub * 64;
    const char* gbase = zn + (size_t)cc * 512;

    { // preload tile 0
        uint4 r0 = *(const uint4*)(gbase + gofs + 0);
        uint4 r1 = *(const uint4*)(gbase + gofs + 16);
        uint4 r2 = *(const uint4*)(gbase + gofs + 32);
        uint4 r3 = *(const uint4*)(gbase + gofs + 48);
        *(uint4*)(lds + lofs + 0)  = r0;
        *(uint4*)(lds + lofs + 16) = r1;
        *(uint4*)(lds + lofs + 32) = r2;
        *(uint4*)(lds + lofs + 48) = r3;
    }
    __syncthreads();

    const int NT = CCHUNK / CT;  // 32
    for (int t = 0; t < NT; t++) {
        char* cur = lds + (t & 1) * LDSBUF;
        char* nxt = lds + ((t + 1) & 1) * LDSBUF;
        uint4 s0, s1, s2, s3;
        if (t + 1 < NT) {
            const char* g = gbase + (size_t)(t + 1) * CT * 512;
            s0 = *(const uint4*)(g + gofs + 0);
            s1 = *(const uint4*)(g + gofs + 16);
            s2 = *(const uint4*)(g + gofs + 32);
            s3 = *(const uint4*)(g + gofs + 48);
        }
        const char* bp = cur + l15 * LDSROW + quad * 16;
        bfrag8 bf[8];
        #pragma unroll
        for (int ks = 0; ks < 8; ks++)
            bf[ks] = *(const bfrag8*)(bp + ks * 64);

        facc4 acc[4];
        #pragma unroll
        for (int s = 0; s < 4; s++) acc[s] = (facc4){0.f, 0.f, 0.f, 0.f};
        #pragma unroll
        for (int ks = 0; ks < 8; ks++)
            #pragma unroll
            for (int s = 0; s < 4; s++)
                acc[s] = __builtin_amdgcn_mfma_f32_16x16x32_bf16(a[s][ks], bf[ks], acc[s], 0, 0, 0);

        int ctile = cc + t * CT;
        int gcol = ctile + l15;
        bool isdiag = (ctile >> 6) == (row0 >> 6);           // wave-uniform
        bool ispos  = (ctile >> 6) == ((row0 ^ BATCH) >> 6); // wave-uniform
        if (isdiag) {
            #pragma unroll
            for (int s = 0; s < 4; s++)
                #pragma unroll
                for (int r = 0; r < 4; r++) {
                    int grow = row0 + s * 16 + quad * 4 + r;
                    float e = __builtin_amdgcn_exp2f(acc[s][r] * KEXP);
                    if (gcol == grow) e = 0.0f;
                    es[s][r] += e;
                }
        } else if (ispos) {
            #pragma unroll
            for (int s = 0; s < 4; s++)
                #pragma unroll
                for (int r = 0; r < 4; r++) {
                    int grow = row0 + s * 16 + quad * 4 + r;
                    float d = acc[s][r];
                    es[s][r] += __builtin_amdgcn_exp2f(d * KEXP);
                    if (gcol == (grow ^ BATCH)) ps[s][r] += d;
                }
        } else {
            #pragma unroll
            for (int s = 0; s < 4; s++)
                #pragma unroll
                for (int r = 0; r < 4; r++)
                    es[s][r] += __builtin_amdgcn_exp2f(acc[s][r] * KEXP);
        }

        if (t + 1 < NT) {
            *(uint4*)(nxt + lofs + 0)  = s0;
            *(uint4*)(nxt + lofs + 16) = s1;
            *(uint4*)(nxt + lofs + 32) = s2;
            *(uint4*)(nxt + lofs + 48) = s3;
        }
        __syncthreads();
    }

    // reduce across the 16 column-lanes; write per-chunk expsum, pos once.
    bool poswave = ((unsigned)((row0 ^ BATCH) - cc) < (unsigned)CCHUNK);
    #pragma unroll
    for (int s = 0; s < 4; s++)
        #pragma unroll
        for (int r = 0; r < 4; r++) {
            float e = es[s][r], p = ps[s][r];
            #pragma unroll
            for (int m = 1; m < 16; m <<= 1) {
                e += __shfl_xor(e, m);
                p += __shfl_xor(p, m);
            }
            if (l15 == 0) {
                int grow = row0 + s * 16 + quad * 4 + r;
                ep[(size_t)chunk * N_ROWS + grow] = e;
                if (poswave) pp[grow] = p;   // raw dot; scaled at finalize
            }
        }

    // ---- fused finalize: last block to finish does the final reduce ----
    __threadfence();
    __syncthreads();
    __shared__ unsigned lastflag;
    if (tid == 0) lastflag = (atomicAdd(done, 1u) == (unsigned)(NBLOCKS - 1)) ? 1u : 0u;
    __syncthreads();
    if (lastflag) {
        __threadfence();
        const volatile float* epv = ep;
        const volatile float* ppv = pp;
        float acc2 = 0.0f;
        for (int k = 0; k < N_ROWS / 128; k++) {
            int i = tid + 128 * k;
            float e = 0.0f;
            #pragma unroll
            for (int c = 0; c < NCHUNK; c++) e += epv[(size_t)c * N_ROWS + i];
            acc2 += __logf(e) - 2.0f * ppv[i];
        }
        #pragma unroll
        for (int m = 32; m; m >>= 1) acc2 += __shfl_xor(acc2, m);
        __shared__ float wsum[2];
        if ((tid & 63) == 0) wsum[tid >> 6] = acc2;
        __syncthreads();
        if (tid == 0) out[0] = (wsum[0] + wsum[1]) * (1.0f / N_ROWS);
    }
}

extern "C" void kernel_launch(void* const* d_in, const int* in_sizes, int n_in,
                              void* d_out, int out_size, void* d_ws, size_t ws_size,
                              hipStream_t stream) {
    const float* zA = (const float*)d_in[0];
    const float* zB = (const float*)d_in[1];
    float* out = (float*)d_out;
    char* ws = (char*)d_ws;
    __hip_bfloat16* zn = (__hip_bfloat16*)ws;                     // 4 MB
    float* ep = (float*)(ws + (size_t)N_ROWS * DIM * 2);          // 16*8192 floats
    float* pp = ep + (size_t)NCHUNK * N_ROWS;                     // 8192 floats
    unsigned* done = (unsigned*)(pp + N_ROWS);                    // 1 uint

    normalize_kernel<<<N_ROWS / 4, 256, 0, stream>>>(zA, zB, zn, done);
    dim3 grid(N_ROWS / MTILE, NCHUNK);
    ntxent_main<<<grid, 128, 0, stream>>>(zn, ep, pp, done, out);
}

// Round 6
// 272.331 us; speedup vs baseline: 2.3714x; 2.3714x over previous
//
#include <hip/hip_runtime.h>
#include <hip/hip_bf16.h>

#define N_ROWS 8192
#define BATCH 4096
#define DIM 256

#define MTILE 256       // rows per block (4 waves x 64 rows)
#define NCHUNK 16       // col chunks
#define CCHUNK 512      // cols per chunk
#define CT 32           // cols per LDS tile (2 MFMA B-frags)
#define LDSROW 528      // 512 data bytes + 16 pad (2-way conflict = free)
#define LDSBUF (CT * LDSROW)
#define NBLOCKS (32 * NCHUNK)
#define KEXP 2.8853900817779268f   // 2*log2(e): exp(2*dot) = exp2(dot*KEXP)

typedef __attribute__((ext_vector_type(8))) short bfrag8;
typedef __attribute__((ext_vector_type(4))) float facc4;

// ---------------- Kernel A: normalize + cast to bf16 -------------------
__global__ __launch_bounds__(256) void normalize_kernel(
    const float* __restrict__ zA, const float* __restrict__ zB,
    __hip_bfloat16* __restrict__ zn, unsigned* __restrict__ done) {
    int tid = threadIdx.x;
    int wave = tid >> 6, lane = tid & 63;
    int row = blockIdx.x * 4 + wave;
    if (blockIdx.x == 0 && tid == 0) *done = 0u;   // counter for fused finalize
    const float* src = (row < BATCH) ? (zA + (size_t)row * DIM)
                                     : (zB + (size_t)(row - BATCH) * DIM);
    float4 v = ((const float4*)src)[lane];
    float ss = v.x * v.x + v.y * v.y + v.z * v.z + v.w * v.w;
    #pragma unroll
    for (int m = 32; m; m >>= 1) ss += __shfl_xor(ss, m);
    float inv = 1.0f / fmaxf(sqrtf(ss), 1e-8f);
    union { ushort4 u; __hip_bfloat16 h[4]; } o;
    o.h[0] = __float2bfloat16(v.x * inv);
    o.h[1] = __float2bfloat16(v.y * inv);
    o.h[2] = __float2bfloat16(v.z * inv);
    o.h[3] = __float2bfloat16(v.w * inv);
    ((ushort4*)zn)[(size_t)row * (DIM / 4) + lane] = o.u;
}

// ---------------- Kernel B: streaming sim + exp-sum + fused finalize ----
// grid (32 row-blocks, 16 col chunks); block 256 = 4 waves x 64 rows.
__global__ __launch_bounds__(256, 2) void ntxent_main(
    const __hip_bfloat16* __restrict__ zn_,
    float* __restrict__ ep, float* __restrict__ pp,
    unsigned* __restrict__ done, float* __restrict__ out) {
    const char* zn = (const char*)zn_;
    __shared__ char lds[2 * LDSBUF] __attribute__((aligned(16)));
    int tid = threadIdx.x, lane = tid & 63, wave = tid >> 6;
    int quad = lane >> 4, l15 = lane & 15;
    int row0 = blockIdx.x * MTILE + wave * 64;   // 64-aligned
    int chunk = blockIdx.y;
    int cc = chunk * CCHUNK;

    // A fragments: 4 tiles of 16 rows. row = row0+s*16+l15, k = ks*32+quad*8+j
    bfrag8 a[4][8];
    #pragma unroll
    for (int s = 0; s < 4; s++) {
        const char* ap = zn + (size_t)(row0 + s * 16 + l15) * 512 + quad * 16;
        #pragma unroll
        for (int ks = 0; ks < 8; ks++)
            a[s][ks] = *(const bfrag8*)(ap + ks * 64);
    }

    float es[4][4], ps[4][4];
    #pragma unroll
    for (int s = 0; s < 4; s++)
        #pragma unroll
        for (int r = 0; r < 4; r++) { es[s][r] = 0.f; ps[s][r] = 0.f; }

    // staging: tile = 32 cols x 512B = 16KB; 256 threads x 4 x 16B
    int col0 = tid >> 5, j0 = tid & 31;
    unsigned lofs[4], gofs[4];
    #pragma unroll
    for (int k = 0; k < 4; k++) {
        lofs[k] = (col0 + 8 * k) * LDSROW + j0 * 16;
        gofs[k] = (col0 + 8 * k) * 512 + j0 * 16;
    }
    const char* gbase = zn + (size_t)cc * 512;

    { // preload tile 0
        #pragma unroll
        for (int k = 0; k < 4; k++) {
            uint4 r = *(const uint4*)(gbase + gofs[k]);
            *(uint4*)(lds + lofs[k]) = r;
        }
    }
    __syncthreads();

    const int NT = CCHUNK / CT;  // 16
    for (int t = 0; t < NT; t++) {
        char* cur = lds + (t & 1) * LDSBUF;
        char* nxt = lds + ((t + 1) & 1) * LDSBUF;
        uint4 st[4];
        if (t + 1 < NT) {
            const char* g = gbase + (size_t)(t + 1) * CT * 512;
            #pragma unroll
            for (int k = 0; k < 4; k++)
                st[k] = *(const uint4*)(g + gofs[k]);
        }

        facc4 acc[2][4];
        #pragma unroll
        for (int h = 0; h < 2; h++)
            #pragma unroll
            for (int s = 0; s < 4; s++) acc[h][s] = (facc4){0.f, 0.f, 0.f, 0.f};

        #pragma unroll
        for (int h = 0; h < 2; h++) {
            const char* bp = cur + (l15 + 16 * h) * LDSROW + quad * 16;
            bfrag8 bf[8];
            #pragma unroll
            for (int ks = 0; ks < 8; ks++)
                bf[ks] = *(const bfrag8*)(bp + ks * 64);
            #pragma unroll
            for (int ks = 0; ks < 8; ks++)
                #pragma unroll
                for (int s = 0; s < 4; s++)
                    acc[h][s] = __builtin_amdgcn_mfma_f32_16x16x32_bf16(a[s][ks], bf[ks], acc[h][s], 0, 0, 0);
        }

        int ctile = cc + t * CT;
        bool isdiag = (ctile >> 6) == (row0 >> 6);           // wave-uniform
        bool ispos  = (ctile >> 6) == ((row0 ^ BATCH) >> 6); // wave-uniform
        #pragma unroll
        for (int h = 0; h < 2; h++) {
            int gcol = ctile + 16 * h + l15;
            if (isdiag) {
                #pragma unroll
                for (int s = 0; s < 4; s++)
                    #pragma unroll
                    for (int r = 0; r < 4; r++) {
                        int grow = row0 + s * 16 + quad * 4 + r;
                        float e = __builtin_amdgcn_exp2f(acc[h][s][r] * KEXP);
                        if (gcol == grow) e = 0.0f;
                        es[s][r] += e;
                    }
            } else if (ispos) {
                #pragma unroll
                for (int s = 0; s < 4; s++)
                    #pragma unroll
                    for (int r = 0; r < 4; r++) {
                        int grow = row0 + s * 16 + quad * 4 + r;
                        float d = acc[h][s][r];
                        es[s][r] += __builtin_amdgcn_exp2f(d * KEXP);
                        if (gcol == (grow ^ BATCH)) ps[s][r] += d;
                    }
            } else {
                #pragma unroll
                for (int s = 0; s < 4; s++)
                    #pragma unroll
                    for (int r = 0; r < 4; r++)
                        es[s][r] += __builtin_amdgcn_exp2f(acc[h][s][r] * KEXP);
            }
        }

        if (t + 1 < NT) {
            #pragma unroll
            for (int k = 0; k < 4; k++)
                *(uint4*)(nxt + lofs[k]) = st[k];
        }
        __syncthreads();
    }

    // reduce across the 16 column-lanes; write per-chunk expsum, pos once.
    bool poswave = ((unsigned)((row0 ^ BATCH) - cc) < (unsigned)CCHUNK);
    #pragma unroll
    for (int s = 0; s < 4; s++)
        #pragma unroll
        for (int r = 0; r < 4; r++) {
            float e = es[s][r], p = ps[s][r];
            #pragma unroll
            for (int m = 1; m < 16; m <<= 1) {
                e += __shfl_xor(e, m);
                p += __shfl_xor(p, m);
            }
            if (l15 == 0) {
                int grow = row0 + s * 16 + quad * 4 + r;
                ep[(size_t)chunk * N_ROWS + grow] = e;
                if (poswave) pp[grow] = p;   // raw cosine; x2 at finalize
            }
        }

    // ---- fused finalize: last block to finish does the final reduce ----
    __threadfence();
    __syncthreads();
    __shared__ unsigned lastflag;
    if (tid == 0) lastflag = (atomicAdd(done, 1u) == (unsigned)(NBLOCKS - 1)) ? 1u : 0u;
    __syncthreads();
    if (lastflag) {
        __threadfence();
        const volatile float* epv = ep;
        const volatile float* ppv = pp;
        float acc2 = 0.0f;
        for (int k = 0; k < N_ROWS / 256; k++) {
            int i = tid + 256 * k;
            float e = 0.0f;
            #pragma unroll
            for (int c = 0; c < NCHUNK; c++) e += epv[(size_t)c * N_ROWS + i];
            acc2 += __logf(e) - 2.0f * ppv[i];
        }
        #pragma unroll
        for (int m = 32; m; m >>= 1) acc2 += __shfl_xor(acc2, m);
        __shared__ float wsum[4];
        if ((tid & 63) == 0) wsum[tid >> 6] = acc2;
        __syncthreads();
        if (tid == 0)
            out[0] = (wsum[0] + wsum[1] + wsum[2] + wsum[3]) * (1.0f / N_ROWS);
    }
}

extern "C" void kernel_launch(void* const* d_in, const int* in_sizes, int n_in,
                              void* d_out, int out_size, void* d_ws, size_t ws_size,
                              hipStream_t stream) {
    const float* zA = (const float*)d_in[0];
    const float* zB = (const float*)d_in[1];
    float* out = (float*)d_out;
    char* ws = (char*)d_ws;
    __hip_bfloat16* zn = (__hip_bfloat16*)ws;                     // 4 MB
    float* ep = (float*)(ws + (size_t)N_ROWS * DIM * 2);          // 16*8192 floats
    float* pp = ep + (size_t)NCHUNK * N_ROWS;                     // 8192 floats
    unsigned* done = (unsigned*)(pp + N_ROWS);                    // 1 uint

    normalize_kernel<<<N_ROWS / 4, 256, 0, stream>>>(zA, zB, zn, done);
    dim3 grid(N_ROWS / MTILE, NCHUNK);
    ntxent_main<<<grid, 256, 0, stream>>>(zn, ep, pp, done, out);
}